// Round 6
// baseline (349.907 us; speedup 1.0000x reference)
//
#include <hip/hip_runtime.h>
#include <hip/hip_bf16.h>
#include <hip/hip_fp16.h>

#define SEQ    2048
#define DMODEL 2048
#define NH     16
#define NKV    4
#define HD     128
#define NTOT   3072   // DMODEL + 2*NKV*HD
#define MROWS  4096   // B*SEQ

typedef __attribute__((ext_vector_type(4))) float f32x4;
typedef __attribute__((ext_vector_type(8))) __bf16 bf16x8;
typedef __attribute__((ext_vector_type(4))) _Float16 f16x4;
typedef __attribute__((ext_vector_type(8))) unsigned short u16x8;
typedef __attribute__((ext_vector_type(4))) unsigned short u16x4;

__device__ __forceinline__ void async_copy16(const void* g, void* l) {
  __builtin_amdgcn_global_load_lds(
      (const __attribute__((address_space(1))) void*)g,
      (__attribute__((address_space(3))) void*)l, 16, 0, 0);
}

__device__ __forceinline__ unsigned short fto16(float f) {
  __hip_bfloat16 h = __float2bfloat16(f);
  return *(unsigned short*)&h;
}

__device__ __forceinline__ float b2f(unsigned short u) {
  unsigned int t = (unsigned int)u << 16;
  float f;
  __builtin_memcpy(&f, &t, 4);
  return f;
}

// ---------------- fake-quant (all 4 weights in one launch) ----------------
__global__ __launch_bounds__(256) void fq_kernel(const float* __restrict__ Wq,
                                                 const float* __restrict__ Wk,
                                                 const float* __restrict__ Wv,
                                                 const float* __restrict__ Wp,
                                                 unsigned short* __restrict__ Wcat,
                                                 unsigned short* __restrict__ Wpq) {
  int g = blockIdx.x * 4 + (threadIdx.x >> 6);
  int lane = threadIdx.x & 63;
  const float* W;
  unsigned short* out;
  int blk;
  if (g < 32768)      { W = Wq; out = Wcat;                          blk = g; }
  else if (g < 40960) { W = Wk; out = Wcat + (size_t)2048 * 2048;    blk = g - 32768; }
  else if (g < 49152) { W = Wv; out = Wcat + (size_t)2560 * 2048;    blk = g - 40960; }
  else                { W = Wp; out = Wpq;                           blk = g - 49152; }
  const float* p = W + (size_t)blk * 128 + lane * 2;
  float w0 = p[0], w1 = p[1];
  float m = fmaxf(fabsf(w0), fabsf(w1));
#pragma unroll
  for (int o = 32; o; o >>= 1) m = fmaxf(m, __shfl_xor(m, o));
  float s = fmaxf(m / 31.0f, 1e-12f);
  s = __half2float(__float2half(s));        // fp16 RNE round of scale
  s = fmaxf(s, 6.103515625e-05f);           // fp16 tiny
  float q0 = rintf(fminf(fmaxf(w0 / s, -32.0f), 31.0f)) * s;
  float q1 = rintf(fminf(fmaxf(w1 / s, -32.0f), 31.0f)) * s;
  unsigned short* o16 = out + (size_t)blk * 128 + lane * 2;
  o16[0] = fto16(q0);
  o16[1] = fto16(q1);
}

// ---------------- fp32 -> bf16 convert ----------------
__global__ __launch_bounds__(256) void conv_kernel(const float* __restrict__ in,
                                                   unsigned short* __restrict__ out,
                                                   int n) {
  int i = (blockIdx.x * blockDim.x + threadIdx.x) * 4;
  if (i >= n) return;
  float4 v = *(const float4*)(in + i);
  ushort4 o;
  o.x = fto16(v.x); o.y = fto16(v.y); o.z = fto16(v.z); o.w = fto16(v.w);
  *(ushort4*)(out + i) = o;
}

// ---------------- bf16 MFMA GEMM, C[m,n] = sum_k A[m,k]*B[n,k] ----------------
// LDS swizzle: 16B granules; rowpair RP=row>>1 holds 8 granules gg' = gg ^ (RP&7),
// gg = ((row&1)<<2)|g. global_load_lds dest stays linear; the SOURCE address is
// permuted per-lane instead. Frag reads become bank-rotating (2-way = free).
#define BM 128
#define BN 128
#define BK 32
template <typename OT>
__global__ __launch_bounds__(256) void gemm_bt(const unsigned short* __restrict__ A,
                                               const unsigned short* __restrict__ Bm,
                                               OT* __restrict__ C,
                                               int M, int N, int K) {
  __shared__ unsigned short As[BM * BK];
  __shared__ unsigned short Bs[BN * BK];
  const int tid = threadIdx.x;
  const int wave = tid >> 6, lane = tid & 63;
  const int quad = lane >> 4, l16 = lane & 15;
  const int m0 = blockIdx.x * BM, n0 = blockIdx.y * BN;
  const int wm = (wave >> 1) * 64, wn = (wave & 1) * 64;

  const unsigned short* Ag = A + (size_t)m0 * K;
  const unsigned short* Bg = Bm + (size_t)n0 * K;

  f32x4 acc[4][4];
#pragma unroll
  for (int i = 0; i < 4; i++)
#pragma unroll
    for (int j = 0; j < 4; j++) acc[i][j] = f32x4{0.f, 0.f, 0.f, 0.f};

  // swizzled staging source mapping (dest = linear lane*16B)
  const int rp  = lane >> 3;            // rowpair within 16-row segment
  const int ggs = (lane & 7) ^ rp;      // source combined granule
  const int sro = rp * 2 + (ggs >> 2);  // source row within segment
  const int sco = (ggs & 3) * 8;        // source col (elems)
  const int seg0 = wave * 2, seg1 = seg0 + 1;
  unsigned short* lA0 = &As[seg0 * 512];
  unsigned short* lA1 = &As[seg1 * 512];
  unsigned short* lB0 = &Bs[seg0 * 512];
  unsigned short* lB1 = &Bs[seg1 * 512];
  const unsigned short* gA0 = Ag + (size_t)(seg0 * 16 + sro) * K + sco;
  const unsigned short* gA1 = Ag + (size_t)(seg1 * 16 + sro) * K + sco;
  const unsigned short* gB0 = Bg + (size_t)(seg0 * 16 + sro) * K + sco;
  const unsigned short* gB1 = Bg + (size_t)(seg1 * 16 + sro) * K + sco;

  // frag read offset (row = wm/wn + t*16 + l16, g = quad)
  const int fbase = (l16 >> 1) * 64 + ((((((l16 & 1) << 2) | quad)) ^ ((l16 >> 1) & 7)) << 3);

  for (int k0 = 0; k0 < K; k0 += BK) {
    __syncthreads();
    async_copy16(gA0 + k0, lA0);
    async_copy16(gA1 + k0, lA1);
    async_copy16(gB0 + k0, lB0);
    async_copy16(gB1 + k0, lB1);
    __syncthreads();
    bf16x8 af[4], bf[4];
#pragma unroll
    for (int t = 0; t < 4; t++)
      af[t] = *(const bf16x8*)&As[(wm + t * 16) * 32 + fbase];
#pragma unroll
    for (int t = 0; t < 4; t++)
      bf[t] = *(const bf16x8*)&Bs[(wn + t * 16) * 32 + fbase];
#pragma unroll
    for (int i = 0; i < 4; i++)
#pragma unroll
      for (int j = 0; j < 4; j++)
        acc[i][j] = __builtin_amdgcn_mfma_f32_16x16x32_bf16(af[i], bf[j], acc[i][j], 0, 0, 0);
  }
#pragma unroll
  for (int i = 0; i < 4; i++) {
    int row_base = m0 + wm + i * 16 + quad * 4;
#pragma unroll
    for (int j = 0; j < 4; j++) {
      int col = n0 + wn + j * 16 + l16;
#pragma unroll
      for (int r = 0; r < 4; r++) {
        if constexpr (sizeof(OT) == 2)
          C[(size_t)(row_base + r) * N + col] = fto16(acc[i][j][r]);
        else
          C[(size_t)(row_base + r) * N + col] = acc[i][j][r];
      }
    }
  }
}

// ---------------- RMSNorm + RoPE + gain (Q,K only), bf16 in/out ----------------
#define QSCALE 0.12751791437524245f   // (1/sqrt(128)) * log2(e)
__global__ __launch_bounds__(256) void normrope_kernel(const unsigned short* __restrict__ qkvb,
                                                       const float* __restrict__ qgain,
                                                       unsigned short* __restrict__ qbuf,
                                                       unsigned short* __restrict__ kbuf) {
  const int i = blockIdx.x;            // token 0..4095
  const int bz = i >> 11, tok = i & 2047;
  const int wave = threadIdx.x >> 6, lane = threadIdx.x & 63;
  const unsigned short* row = qkvb + (size_t)i * NTOT;

  // 10000^(-2*lane/128) = 2^(-2*lane*log2(1e4)/128)
  float invf = exp2f(-0.10381025296f * (float)(2 * lane));
  float freq = (float)tok * invf;
  float cs, sn;
  __sincosf(freq, &sn, &cs);

  for (int slot = wave; slot < 20; slot += 4) {
    if (slot < 16) {                   // q heads: norm + rope + gain*scale
      int hh = slot;
      const unsigned short* src = row + hh * HD;
      float x1 = b2f(src[lane]), x2 = b2f(src[lane + 64]);
      float ss = x1 * x1 + x2 * x2;
#pragma unroll
      for (int o = 32; o; o >>= 1) ss += __shfl_xor(ss, o);
      float rn = rsqrtf(ss * (1.0f / 128.0f) + 1.1920929e-07f);
      float n1 = x1 * rn, n2 = x2 * rn;
      float g = qgain[hh] * QSCALE;
      unsigned short* dst = qbuf + ((size_t)(bz * NH + hh) * SEQ + tok) * HD;
      dst[lane]      = fto16((n1 * cs + n2 * sn) * g);
      dst[lane + 64] = fto16((-n1 * sn + n2 * cs) * g);
    } else {                           // k heads: norm + rope
      int hh = slot - 16;
      const unsigned short* src = row + DMODEL + hh * HD;
      float x1 = b2f(src[lane]), x2 = b2f(src[lane + 64]);
      float ss = x1 * x1 + x2 * x2;
#pragma unroll
      for (int o = 32; o; o >>= 1) ss += __shfl_xor(ss, o);
      float rn = rsqrtf(ss * (1.0f / 128.0f) + 1.1920929e-07f);
      float n1 = x1 * rn, n2 = x2 * rn;
      unsigned short* dst = kbuf + ((size_t)(bz * NKV + hh) * SEQ + tok) * HD;
      dst[lane]      = fto16(n1 * cs + n2 * sn);
      dst[lane + 64] = fto16(-n1 * sn + n2 * cs);
    }
  }
}

// ---------------- V transpose: bf16 qkv v-section -> f16 V^T [b,kvh,d,s] ----------------
__global__ __launch_bounds__(256) void vtrans_kernel(const unsigned short* __restrict__ qkvb,
                                                     unsigned short* __restrict__ vtb) {
  __shared__ unsigned short T[64 * 72];
  const int s0 = blockIdx.x * 64;
  const int d0 = blockIdx.y * 64;
  const int bz = blockIdx.z >> 2, h = blockIdx.z & 3;
  const int tid = threadIdx.x;
#pragma unroll
  for (int i = 0; i < 2; ++i) {
    int c = i * 256 + tid;
    int s = c >> 3, ch = c & 7;
    const unsigned short* src =
        qkvb + (size_t)(bz * SEQ + s0 + s) * NTOT + DMODEL + 512 + h * HD + d0 + ch * 8;
    u16x8 sv = *(const u16x8*)src;
    u16x8 v;
#pragma unroll
    for (int j = 0; j < 8; ++j) {      // bf16 -> f16
      __half hf = __float2half(b2f(sv[j]));
      unsigned short b;
      __builtin_memcpy(&b, &hf, 2);
      v[j] = b;
    }
    *(u16x8*)&T[s * 72 + ch * 8] = v;
  }
  __syncthreads();
  unsigned short* outg = vtb + (size_t)(bz * NKV + h) * HD * SEQ;
#pragma unroll
  for (int i = 0; i < 2; ++i) {
    int c = i * 256 + tid;
    int d = c >> 3, sc = c & 7;
    u16x8 v;
#pragma unroll
    for (int j = 0; j < 8; ++j) v[j] = T[(sc * 8 + j) * 72 + d];
    *(u16x8*)(outg + (size_t)(d0 + d) * SEQ + s0 + sc * 8) = v;
  }
}

// ---------------- flash attention: K/V double-buffered, register-P PV ----------
// PV uses mfma_f32_16x16x16_f16: its B-fragment (k = quad*4+j) is exactly the
// S^T C-layout each lane already holds -> P never round-trips through LDS.
// LDS = K dbuf 32K + V dbuf 32K = 64KB, one barrier per k-tile.
__global__ __launch_bounds__(256, 2) void attn_kernel(const unsigned short* __restrict__ qb,
                                                      const unsigned short* __restrict__ kb,
                                                      const unsigned short* __restrict__ vtb,
                                                      unsigned short* __restrict__ yb) {
  __shared__ unsigned short Ks[2][64 * 128];   // [kpos][d] bf16, swizzled
  __shared__ unsigned short Vt[2][128 * 64];   // [d][kpos] f16,  swizzled

  const int bx = blockIdx.x;
  const int h = blockIdx.y;
  const int bz = blockIdx.z;
  const int qt = bz ? bx : (15 - bx);          // CU partner gets the complement
  const int tid = threadIdx.x;
  const int wave = tid >> 6, lane = tid & 63;
  const int quad = lane >> 4, l16 = lane & 15;
  const int q0 = qt * 128;
  const int base0 = q0 + wave * 32;
  const int kdiag0 = base0 >> 6, kdiag1 = (base0 + 16) >> 6;

  const unsigned short* qg = qb + (size_t)(bz * NH + h) * SEQ * HD;
  const unsigned short* kg = kb + (size_t)(bz * NKV + (h >> 2)) * SEQ * HD;
  const unsigned short* vg = vtb + (size_t)(bz * NKV + (h >> 2)) * HD * SEQ;

  bf16x8 qf[2][4];
#pragma unroll
  for (int sg = 0; sg < 2; ++sg)
#pragma unroll
    for (int ds = 0; ds < 4; ++ds)
      qf[sg][ds] = *(const bf16x8*)(qg + (size_t)(base0 + sg * 16 + l16) * HD + ds * 32 + quad * 8);

  f32x4 oacc[2][8];
#pragma unroll
  for (int sg = 0; sg < 2; ++sg)
#pragma unroll
    for (int j = 0; j < 8; ++j) oacc[sg][j] = f32x4{0.f, 0.f, 0.f, 0.f};
  float m_i[2] = {-__builtin_inff(), -__builtin_inff()};
  float l_i[2] = {0.f, 0.f};

  // staging thread mapping
  const int krw = tid >> 4, kgr = tid & 15;   // K: 16 rows/iter
  const int vdw = tid >> 3, vgr = tid & 7;    // V: 32 d/iter
  const int nkt = 2 * qt + 2;

  u16x8 pk[4], pv[4];
#pragma unroll
  for (int i = 0; i < 4; ++i)
    pk[i] = *(const u16x8*)(kg + (size_t)(i * 16 + krw) * HD + kgr * 8);
#pragma unroll
  for (int i = 0; i < 4; ++i)
    pv[i] = *(const u16x8*)(vg + (size_t)(i * 32 + vdw) * SEQ + vgr * 8);
#pragma unroll
  for (int i = 0; i < 4; ++i) {
    int row = i * 16 + krw;
    *(u16x8*)&Ks[0][row * 128 + ((kgr ^ (row & 15)) << 3)] = pk[i];
  }
#pragma unroll
  for (int i = 0; i < 4; ++i) {
    int d = i * 32 + vdw;
    *(u16x8*)&Vt[0][d * 64 + ((vgr ^ (d & 7)) << 3)] = pv[i];
  }
  __syncthreads();

  for (int kt = 0; kt < nkt; ++kt) {
    const int cur = kt & 1;
    const unsigned short* KsC = &Ks[cur][0];
    const unsigned short* VtC = &Vt[cur][0];
    const bool pre = (kt + 1 < nkt);

    if (pre) {                         // global prefetch of next tile (in regs)
#pragma unroll
      for (int i = 0; i < 4; ++i)
        pk[i] = *(const u16x8*)(kg + (size_t)((kt + 1) * 64 + i * 16 + krw) * HD + kgr * 8);
#pragma unroll
      for (int i = 0; i < 4; ++i)
        pv[i] = *(const u16x8*)(vg + (size_t)(i * 32 + vdw) * SEQ + (kt + 1) * 64 + vgr * 8);
    }

    const bool act0 = (kt <= kdiag0);
    if (kt <= kdiag1) {
      // ---- S^T = K * Q^T ----
      f32x4 st[2][4];
#pragma unroll
      for (int sg = 0; sg < 2; ++sg)
#pragma unroll
        for (int mt = 0; mt < 4; ++mt) st[sg][mt] = f32x4{0.f, 0.f, 0.f, 0.f};
#pragma unroll
      for (int mt = 0; mt < 4; ++mt)
#pragma unroll
        for (int ds = 0; ds < 4; ++ds) {
          bf16x8 kf = *(const bf16x8*)&KsC[(mt * 16 + l16) * 128 + ((((ds << 2) + quad) ^ l16) << 3)];
          if (act0)
            st[0][mt] = __builtin_amdgcn_mfma_f32_16x16x32_bf16(kf, qf[0][ds], st[0][mt], 0, 0, 0);
          st[1][mt] = __builtin_amdgcn_mfma_f32_16x16x32_bf16(kf, qf[1][ds], st[1][mt], 0, 0, 0);
        }

      // ---- online softmax per subgroup; P stays in registers as f16 B-frags ----
      f16x4 bp[2][4];
#pragma unroll
      for (int sg = 0; sg < 2; ++sg) {
        if (sg == 0 && !act0) continue;
        const int qrow = base0 + sg * 16 + l16;
        float p[4][4];
        float mx = -__builtin_inff();
        if (kt == (sg ? kdiag1 : kdiag0)) {
#pragma unroll
          for (int mt = 0; mt < 4; ++mt)
#pragma unroll
            for (int r = 0; r < 4; ++r) {
              int kp = kt * 64 + mt * 16 + quad * 4 + r;
              float v = (kp <= qrow) ? st[sg][mt][r] : -__builtin_inff();
              p[mt][r] = v;
              mx = fmaxf(mx, v);
            }
        } else {
#pragma unroll
          for (int mt = 0; mt < 4; ++mt)
#pragma unroll
            for (int r = 0; r < 4; ++r) {
              p[mt][r] = st[sg][mt][r];
              mx = fmaxf(mx, st[sg][mt][r]);
            }
        }
        mx = fmaxf(mx, __shfl_xor(mx, 16));
        mx = fmaxf(mx, __shfl_xor(mx, 32));
        float mnew = fmaxf(m_i[sg], mx);
        float rs = 0.f;
#pragma unroll
        for (int mt = 0; mt < 4; ++mt)
#pragma unroll
          for (int r = 0; r < 4; ++r) {
            float e = exp2f(p[mt][r] - mnew);
            p[mt][r] = e;
            rs += e;
          }
        rs += __shfl_xor(rs, 16);
        rs += __shfl_xor(rs, 32);
        if (__any(mnew > m_i[sg])) {
          float a = exp2f(m_i[sg] - mnew);
#pragma unroll
          for (int j = 0; j < 8; ++j) oacc[sg][j] *= a;
          l_i[sg] = l_i[sg] * a + rs;
        } else {
          l_i[sg] += rs;
        }
        m_i[sg] = mnew;
#pragma unroll
        for (int mt = 0; mt < 4; ++mt) {
          f16x4 w;
#pragma unroll
          for (int r = 0; r < 4; ++r) w[r] = (_Float16)p[mt][r];
          bp[sg][mt] = w;
        }
      }

      // ---- O^T += V^T * P^T via 16x16x16 f16 MFMA (A = V-frag from LDS) ----
#pragma unroll
      for (int mt = 0; mt < 4; ++mt) {
        const int g = 2 * mt + (quad >> 1);
        const int vo = ((g ^ (l16 & 7)) << 3) + (quad & 1) * 4;
#pragma unroll
        for (int dt = 0; dt < 8; ++dt) {
          f16x4 vf = *(const f16x4*)&VtC[(dt * 16 + l16) * 64 + vo];
          if (act0)
            oacc[0][dt] = __builtin_amdgcn_mfma_f32_16x16x16f16(vf, bp[0][mt], oacc[0][dt], 0, 0, 0);
          oacc[1][dt] = __builtin_amdgcn_mfma_f32_16x16x16f16(vf, bp[1][mt], oacc[1][dt], 0, 0, 0);
        }
      }
    }

    if (pre) {                          // store prefetched tile into other buffer
#pragma unroll
      for (int i = 0; i < 4; ++i) {
        int row = i * 16 + krw;
        *(u16x8*)&Ks[cur ^ 1][row * 128 + ((kgr ^ (row & 15)) << 3)] = pk[i];
      }
#pragma unroll
      for (int i = 0; i < 4; ++i) {
        int d = i * 32 + vdw;
        *(u16x8*)&Vt[cur ^ 1][d * 64 + ((vgr ^ (d & 7)) << 3)] = pv[i];
      }
    }
    __syncthreads();
  }

  // epilogue: O^T row = d = dt*16+quad*4+r, col = q = l16; per-lane invl
#pragma unroll
  for (int sg = 0; sg < 2; ++sg) {
    float il = 1.0f / l_i[sg];
    int qrow = base0 + sg * 16 + l16;
#pragma unroll
    for (int dt = 0; dt < 8; ++dt) {
      u16x4 o;
#pragma unroll
      for (int r = 0; r < 4; ++r) o[r] = fto16(oacc[sg][dt][r] * il);
      *(u16x4*)&yb[(size_t)(bz * SEQ + qrow) * DMODEL + h * HD + dt * 16 + quad * 4] = o;
    }
  }
}

extern "C" void kernel_launch(void* const* d_in, const int* in_sizes, int n_in,
                              void* d_out, int out_size, void* d_ws, size_t ws_size,
                              hipStream_t stream) {
  (void)in_sizes; (void)n_in; (void)out_size; (void)ws_size;
  const float* x  = (const float*)d_in[0];
  const float* Wq = (const float*)d_in[1];
  const float* Wk = (const float*)d_in[2];
  const float* Wv = (const float*)d_in[3];
  const float* Wp = (const float*)d_in[4];
  const float* qg = (const float*)d_in[5];
  float* out = (float*)d_out;
  char* ws = (char*)d_ws;

  // workspace layout; yb aliases xb (x consumed by GEMM1 before attn writes y)
  unsigned short* xb   = (unsigned short*)(ws + 0);          // 16.78 MB
  unsigned short* Wcat = (unsigned short*)(ws + 16777216);   // 12.58 MB (Wq|Wk|Wv rows)
  unsigned short* Wpq  = (unsigned short*)(ws + 29360128);   // 8.39 MB
  unsigned short* qkvb = (unsigned short*)(ws + 37748736);   // 25.17 MB (bf16 qkv)
  unsigned short* qbuf = (unsigned short*)(ws + 62914560);   // 16.78 MB
  unsigned short* kbuf = (unsigned short*)(ws + 79691776);   // 4.19 MB
  unsigned short* vtb  = (unsigned short*)(ws + 83886080);   // 4.19 MB (V^T, f16)
  unsigned short* yb   = xb;

  fq_kernel<<<81920 / 4, 256, 0, stream>>>(Wq, Wk, Wv, Wp, Wcat, Wpq);
  conv_kernel<<<8388608 / 1024, 256, 0, stream>>>(x, xb, 8388608);
  gemm_bt<unsigned short><<<dim3(32, 24), 256, 0, stream>>>(xb, Wcat, qkvb, MROWS, NTOT, DMODEL);
  normrope_kernel<<<MROWS, 256, 0, stream>>>(qkvb, qg, qbuf, kbuf);
  vtrans_kernel<<<dim3(32, 2, 8), 256, 0, stream>>>(qkvb, vtb);
  attn_kernel<<<dim3(16, NH, 2), 256, 0, stream>>>(qbuf, kbuf, vtb, yb);
  gemm_bt<float><<<dim3(32, 16), 256, 0, stream>>>(yb, Wpq, out, MROWS, DMODEL, DMODEL);
}